// Round 1
// baseline (146.353 us; speedup 1.0000x reference)
//
#include <hip/hip_runtime.h>

static constexpr int BB = 16;
static constexpr int NN = 256;
static constexpr int DD = 128;

__device__ __forceinline__ float fsig(float x) {
    // sigmoid(x) = 1/(1+exp(-x)); __expf -> v_exp_f32, rcpf -> v_rcp_f32 (~1ulp)
    return __builtin_amdgcn_rcpf(1.0f + __expf(-x));
}

// q = x@Wq^T + bq ; k = x@Wk^T ; v = x@Wv^T   (W stored [e][d], out[b,n,e])
__global__ __launch_bounds__(256) void qkv_kernel(
    const float* __restrict__ x,
    const float* __restrict__ Wq, const float* __restrict__ bq,
    const float* __restrict__ Wk, const float* __restrict__ Wv,
    float* __restrict__ q, float* __restrict__ k, float* __restrict__ v)
{
    __shared__ float xs[16][DD];
    const int b  = blockIdx.x >> 4;          // 16 blocks per batch
    const int r0 = (blockIdx.x & 15) << 4;   // 16-row tile
    const int t  = threadIdx.x;

    const float4* xg = (const float4*)(x + ((size_t)(b * NN + r0)) * DD);
    float4* xsv = (float4*)(&xs[0][0]);
    for (int l = t; l < 16 * DD / 4; l += 256) xsv[l] = xg[l];
    __syncthreads();

    const int e  = t & 127;
    const int rh = t >> 7;                   // 0/1 -> rows rh*8 .. rh*8+7
    const float* xb = &xs[rh * 8][0];

    for (int m = 0; m < 3; ++m) {
        const float* W = (m == 0) ? Wq : (m == 1) ? Wk : Wv;
        float*       o = (m == 0) ? q  : (m == 1) ? k  : v;
        const float bias = (m == 0) ? bq[e] : 0.0f;
        float acc[8];
        #pragma unroll
        for (int r = 0; r < 8; ++r) acc[r] = bias;
        const float4* Wr = (const float4*)(W + (size_t)e * DD);
        #pragma unroll 8
        for (int d4 = 0; d4 < DD / 4; ++d4) {
            const float4 w = Wr[d4];
            const float* xp = xb + d4 * 4;
            #pragma unroll
            for (int r = 0; r < 8; ++r) {
                acc[r] = fmaf(xp[r * DD + 0], w.x,
                         fmaf(xp[r * DD + 1], w.y,
                         fmaf(xp[r * DD + 2], w.z,
                         fmaf(xp[r * DD + 3], w.w, acc[r]))));
            }
        }
        #pragma unroll
        for (int r = 0; r < 8; ++r)
            o[((size_t)(b * NN + r0 + rh * 8 + r)) * DD + e] = acc[r];
    }
}

// One block per (b, tile of 8 j's). 256 threads.
// Phase B: s[i][j] = sum_d sigmoid((k[i,d]+q[j,d])*edge) * We[d]
// Phase C: softmax over i per j (in-wave shuffle reduce)
// Phase D: out[j][d] = sum_i a[j][i] * v[i][d]
__global__ __launch_bounds__(256) void attn_kernel(
    const int* __restrict__ A, const float* __restrict__ We,
    const float* __restrict__ q, const float* __restrict__ k,
    const float* __restrict__ v, float* __restrict__ out)
{
    __shared__ float ks[64][132];   // k tile, reused for v tile (pad 132: conflict-free)
    __shared__ float qs[8][132];
    __shared__ float wes[DD];
    __shared__ float ss[8][260];    // s / a matrix, [j_local][i]

    const int b  = blockIdx.x >> 5;
    const int j0 = (blockIdx.x & 31) << 3;
    const int t  = threadIdx.x;

    // ---- Phase A: stage q rows + We ----
    {
        const float4* qg = (const float4*)(q + ((size_t)(b * NN + j0)) * DD);
        const float4 val = qg[t];                 // 8*128/4 == 256 exactly
        const int row = t >> 5, col = (t & 31) << 2;
        *(float4*)&qs[row][col] = val;
        if (t < 32) {
            const float4 w = ((const float4*)We)[t];
            *(float4*)&wes[t << 2] = w;
        }
    }

    const int il = t >> 2;   // 0..63 : i within tile
    const int jq = t & 3;    // handles j_local = jq and jq+4

    for (int it = 0; it < 4; ++it) {
        const int i0 = it << 6;
        __syncthreads();     // prev-tile reads done (also covers Phase A writes)
        const float4* kg = (const float4*)(k + ((size_t)(b * NN + i0)) * DD);
        for (int l = t; l < 64 * DD / 4; l += 256) {
            const int row = l >> 5, col = (l & 31) << 2;
            *(float4*)&ks[row][col] = kg[l];
        }
        __syncthreads();

        const int arow = ((b * NN) + i0 + il) * NN + j0;
        const float m0 = (A[arow + jq]     == 1) ? 1.0f : 0.0f;
        const float m1 = (A[arow + jq + 4] == 1) ? 1.0f : 0.0f;
        float s0 = 0.0f, s1 = 0.0f;
        #pragma unroll 4
        for (int d4 = 0; d4 < DD / 4; ++d4) {
            const float4 kv = *(const float4*)&ks[il][d4 << 2];
            const float4 wv = *(const float4*)&wes[d4 << 2];
            const float4 q0 = *(const float4*)&qs[jq][d4 << 2];
            const float4 q1 = *(const float4*)&qs[jq + 4][d4 << 2];
            s0 += fsig((kv.x + q0.x) * m0) * wv.x + fsig((kv.y + q0.y) * m0) * wv.y
                + fsig((kv.z + q0.z) * m0) * wv.z + fsig((kv.w + q0.w) * m0) * wv.w;
            s1 += fsig((kv.x + q1.x) * m1) * wv.x + fsig((kv.y + q1.y) * m1) * wv.y
                + fsig((kv.z + q1.z) * m1) * wv.z + fsig((kv.w + q1.w) * m1) * wv.w;
        }
        ss[jq][i0 + il]     = s0;
        ss[jq + 4][i0 + il] = s1;
    }
    __syncthreads();

    // ---- Phase C: softmax over i (axis=1) per j ----
    {
        const int j = t >> 5, c = t & 31;   // 32 lanes per j, 8 i's each
        float vals[8];
        float mx = -1e30f;
        #pragma unroll
        for (int u = 0; u < 8; ++u) { vals[u] = ss[j][c * 8 + u]; mx = fmaxf(mx, vals[u]); }
        #pragma unroll
        for (int o = 16; o > 0; o >>= 1) mx = fmaxf(mx, __shfl_xor(mx, o, 32));
        float sum = 0.0f;
        #pragma unroll
        for (int u = 0; u < 8; ++u) { vals[u] = __expf(vals[u] - mx); sum += vals[u]; }
        #pragma unroll
        for (int o = 16; o > 0; o >>= 1) sum += __shfl_xor(sum, o, 32);
        const float inv = __builtin_amdgcn_rcpf(sum);
        #pragma unroll
        for (int u = 0; u < 8; ++u) ss[j][c * 8 + u] = vals[u] * inv;
    }

    // ---- Phase D: out[j][d] = sum_i a[j][i] * v[i][d] ----
    const int jd = t & 7, cd = t >> 3;      // d = cd*4 .. cd*4+3
    float o0 = 0.f, o1 = 0.f, o2 = 0.f, o3 = 0.f;
    for (int it = 0; it < 4; ++it) {
        const int i0 = it << 6;
        __syncthreads();                    // Phase C ss writes done / prev reads done
        const float4* vg = (const float4*)(v + ((size_t)(b * NN + i0)) * DD);
        for (int l = t; l < 64 * DD / 4; l += 256) {
            const int row = l >> 5, col = (l & 31) << 2;
            *(float4*)&ks[row][col] = vg[l];
        }
        __syncthreads();
        #pragma unroll 8
        for (int i = 0; i < 64; ++i) {
            const float a = ss[jd][i0 + i];
            const float4 vv = *(const float4*)&ks[i][cd << 2];
            o0 = fmaf(a, vv.x, o0);
            o1 = fmaf(a, vv.y, o1);
            o2 = fmaf(a, vv.z, o2);
            o3 = fmaf(a, vv.w, o3);
        }
    }
    const float4 res = make_float4(o0, o1, o2, o3);
    *(float4*)&out[((size_t)(b * NN + j0 + jd)) * DD + (cd << 2)] = res;
}

extern "C" void kernel_launch(void* const* d_in, const int* in_sizes, int n_in,
                              void* d_out, int out_size, void* d_ws, size_t ws_size,
                              hipStream_t stream)
{
    const float* x  = (const float*)d_in[0];
    const int*   A  = (const int*)  d_in[1];
    const float* Wq = (const float*)d_in[2];
    const float* bq = (const float*)d_in[3];
    const float* Wk = (const float*)d_in[4];
    const float* Wv = (const float*)d_in[5];
    const float* We = (const float*)d_in[6];
    float* out = (float*)d_out;

    float* q = (float*)d_ws;
    float* k = q + (size_t)BB * NN * DD;
    float* v = k + (size_t)BB * NN * DD;

    qkv_kernel<<<BB * NN / 16, 256, 0, stream>>>(x, Wq, bq, Wk, Wv, q, k, v);
    attn_kernel<<<BB * (NN / 8), 256, 0, stream>>>(A, We, q, k, v, out);
}